// Round 1
// baseline (828.267 us; speedup 1.0000x reference)
//
#include <hip/hip_runtime.h>
#include <math.h>

// Problem constants (B=2, H=32, S=16384, D=64), fp32 in/out.
#define BH_ 64
#define S_ 16384
#define D_ 64
#define LD_ 68                      // padded LDS row stride (68*4 B = 272 B, 16B-aligned, kills stride-64 bank aliasing)
#define P1_CHUNKS 16
#define P1_ROWS (S_ / P1_CHUNKS)    // 1024 rows per phase-1 block
#define P2_CHUNKS 32
#define P2_ROWS (S_ / P2_CHUNKS)    // 512 rows per phase-2 block

__device__ __forceinline__ float elu1(float x) {
    // elu(x)+1 == x+1 (x>0) else exp(x)
    return x > 0.0f ? x + 1.0f : __expf(x);
}

#define FMA4(s, m, a) { (a).x += (s) * (m).x; (a).y += (s) * (m).y; (a).z += (s) * (m).z; (a).w += (s) * (m).w; }

// ---------------------------------------------------------------------------
// Phase 1: M[bh][dk][dv] = sum_s kf[s][dk] * v[s][dv];  z[bh][dk] = sum_s kf[s][dk]
// grid = (P1_CHUNKS, BH), block = 256. Each thread owns a 4(dk)x4(dv) tile of M.
// ---------------------------------------------------------------------------
__global__ __launch_bounds__(256) void p1_kernel(const float* __restrict__ K,
                                                 const float* __restrict__ V,
                                                 float* __restrict__ Mg,
                                                 float* __restrict__ zg) {
    __shared__ float kf[64 * LD_];
    __shared__ float vf[64 * LD_];
    __shared__ float zpart[4][64];

    const int tid = threadIdx.x;
    const int bh = blockIdx.y;
    const int chunk = blockIdx.x;
    const int ki = tid >> 4;    // dk tile [0,16)
    const int vj = tid & 15;    // dv tile [0,16)
    const int zd = tid & 63;    // column for z partial sums
    const int zq = tid >> 6;    // wave index -> row quarter

    const size_t base = ((size_t)bh * S_ + (size_t)chunk * P1_ROWS) * D_;
    const float* Kb = K + base;
    const float* Vb = V + base;

    float4 acc0 = {0.f,0.f,0.f,0.f}, acc1 = acc0, acc2 = acc0, acc3 = acc0;
    float zacc = 0.f;

    for (int s0 = 0; s0 < P1_ROWS; s0 += 64) {
        __syncthreads();
        // stage 64 rows of K (with elu+1) and V into LDS; coalesced float4 loads
        #pragma unroll
        for (int k = 0; k < 4; ++k) {
            const int row = k * 16 + (tid >> 4);
            const int col = (tid & 15) * 4;
            float4 kv = *(const float4*)(Kb + (size_t)(s0 + row) * D_ + col);
            float4 vv = *(const float4*)(Vb + (size_t)(s0 + row) * D_ + col);
            float4 kx;
            kx.x = elu1(kv.x); kx.y = elu1(kv.y); kx.z = elu1(kv.z); kx.w = elu1(kv.w);
            *(float4*)&kf[row * LD_ + col] = kx;
            *(float4*)&vf[row * LD_ + col] = vv;
        }
        __syncthreads();

        // z: column sums of this stage (wave w sums rows [16w,16w+16) of its column)
        #pragma unroll
        for (int j = 0; j < 16; ++j)
            zacc += kf[(zq * 16 + j) * LD_ + zd];

        // rank-1 outer-product accumulation: 2x ds_read_b128 + 16 FMA per s-row
        #pragma unroll 4
        for (int s = 0; s < 64; ++s) {
            float4 a = *(const float4*)&kf[s * LD_ + 4 * ki];
            float4 b = *(const float4*)&vf[s * LD_ + 4 * vj];
            FMA4(a.x, b, acc0);
            FMA4(a.y, b, acc1);
            FMA4(a.z, b, acc2);
            FMA4(a.w, b, acc3);
        }
    }

    // reduce z across the 4 waves, one atomic per column
    zpart[zq][zd] = zacc;
    __syncthreads();
    if (tid < 64) {
        float z = zpart[0][tid] + zpart[1][tid] + zpart[2][tid] + zpart[3][tid];
        atomicAdd(&zg[bh * 64 + tid], z);
    }

    // M tile writeback: 16 atomics per thread into the per-head 64x64 block
    float* Mb = Mg + (size_t)bh * 4096 + (size_t)(4 * ki) * 64 + 4 * vj;
    atomicAdd(&Mb[0 * 64 + 0], acc0.x); atomicAdd(&Mb[0 * 64 + 1], acc0.y);
    atomicAdd(&Mb[0 * 64 + 2], acc0.z); atomicAdd(&Mb[0 * 64 + 3], acc0.w);
    atomicAdd(&Mb[1 * 64 + 0], acc1.x); atomicAdd(&Mb[1 * 64 + 1], acc1.y);
    atomicAdd(&Mb[1 * 64 + 2], acc1.z); atomicAdd(&Mb[1 * 64 + 3], acc1.w);
    atomicAdd(&Mb[2 * 64 + 0], acc2.x); atomicAdd(&Mb[2 * 64 + 1], acc2.y);
    atomicAdd(&Mb[2 * 64 + 2], acc2.z); atomicAdd(&Mb[2 * 64 + 3], acc2.w);
    atomicAdd(&Mb[3 * 64 + 0], acc3.x); atomicAdd(&Mb[3 * 64 + 1], acc3.y);
    atomicAdd(&Mb[3 * 64 + 2], acc3.z); atomicAdd(&Mb[3 * 64 + 3], acc3.w);
}

// ---------------------------------------------------------------------------
// Phase 2: out[s][dv] = (qf[s] @ M)[dv] / (qf[s] . z)
// grid = (P2_CHUNKS, BH), block = 256. Thread owns 4 s-rows x 4 dv-cols.
// Wave w handles stage rows [16w, 16w+16) for both the matvec and the denominator,
// so the denominator reciprocal moves by intra-wave shuffle (no extra barrier).
// ---------------------------------------------------------------------------
__global__ __launch_bounds__(256) void p2_kernel(const float* __restrict__ Q,
                                                 const float* __restrict__ Mg,
                                                 const float* __restrict__ zg,
                                                 float* __restrict__ Ob) {
    __shared__ float Ms[64 * 64];   // stride 64: reads are single-row -> conflict-free
    __shared__ float qs[64 * LD_];
    __shared__ float zs[64];

    const int tid = threadIdx.x;
    const int bh = blockIdx.y;
    const int chunk = blockIdx.x;
    const int si = tid >> 4;        // s tile [0,16): wave w -> si in [4w,4w+4)
    const int vj = tid & 15;        // dv tile [0,16)
    const int lane = tid & 63;

    // load this head's memory matrix + normalization into LDS
    #pragma unroll
    for (int k = 0; k < 4; ++k)
        *(float4*)&Ms[k * 1024 + tid * 4] =
            *(const float4*)&Mg[(size_t)bh * 4096 + k * 1024 + tid * 4];
    if (tid < 16)
        *(float4*)&zs[tid * 4] = *(const float4*)&zg[bh * 64 + tid * 4];

    const size_t base = ((size_t)bh * S_ + (size_t)chunk * P2_ROWS) * D_;
    const float* Qb = Q + base;
    float* Outb = Ob + base;

    const int drow = (tid >> 6) * 16 + (lane >> 2);  // denominator row (stage-local)
    const int seg = lane & 3;                        // 16-dk segment

    for (int s0 = 0; s0 < P2_ROWS; s0 += 64) {
        __syncthreads();  // also covers initial Ms/zs load
        // stage 64 qf rows
        #pragma unroll
        for (int k = 0; k < 4; ++k) {
            const int row = k * 16 + (tid >> 4);
            const int col = (tid & 15) * 4;
            float4 qv = *(const float4*)(Qb + (size_t)(s0 + row) * D_ + col);
            float4 qx;
            qx.x = elu1(qv.x); qx.y = elu1(qv.y); qx.z = elu1(qv.z); qx.w = elu1(qv.w);
            *(float4*)&qs[row * LD_ + col] = qx;
        }
        __syncthreads();

        // denominator: 4 lanes per row, each sums a 16-dk segment, butterfly-combine
        float dsum = 0.f;
        #pragma unroll
        for (int j = 0; j < 4; ++j) {
            float4 qq = *(const float4*)&qs[drow * LD_ + seg * 16 + j * 4];
            float4 zz = *(const float4*)&zs[seg * 16 + j * 4];
            dsum += qq.x * zz.x + qq.y * zz.y + qq.z * zz.z + qq.w * zz.w;
        }
        dsum += __shfl_xor(dsum, 1);
        dsum += __shfl_xor(dsum, 2);
        const float dinv = 1.0f / dsum;

        // matvec: 4 rows x 4 cols per thread; 8 b128 LDS reads + 64 FMA per 4-dk
        float4 a0 = {0.f,0.f,0.f,0.f}, a1 = a0, a2 = a0, a3 = a0;
        #pragma unroll 2
        for (int dk = 0; dk < 64; dk += 4) {
            float4 m0 = *(const float4*)&Ms[(dk + 0) * 64 + 4 * vj];
            float4 m1 = *(const float4*)&Ms[(dk + 1) * 64 + 4 * vj];
            float4 m2 = *(const float4*)&Ms[(dk + 2) * 64 + 4 * vj];
            float4 m3 = *(const float4*)&Ms[(dk + 3) * 64 + 4 * vj];
            float4 q0 = *(const float4*)&qs[(4 * si + 0) * LD_ + dk];
            float4 q1 = *(const float4*)&qs[(4 * si + 1) * LD_ + dk];
            float4 q2 = *(const float4*)&qs[(4 * si + 2) * LD_ + dk];
            float4 q3 = *(const float4*)&qs[(4 * si + 3) * LD_ + dk];
            FMA4(q0.x, m0, a0); FMA4(q0.y, m1, a0); FMA4(q0.z, m2, a0); FMA4(q0.w, m3, a0);
            FMA4(q1.x, m0, a1); FMA4(q1.y, m1, a1); FMA4(q1.z, m2, a1); FMA4(q1.w, m3, a1);
            FMA4(q2.x, m0, a2); FMA4(q2.y, m1, a2); FMA4(q2.z, m2, a2); FMA4(q2.w, m3, a2);
            FMA4(q3.x, m0, a3); FMA4(q3.y, m1, a3); FMA4(q3.z, m2, a3); FMA4(q3.w, m3, a3);
        }

        // scale by denominator reciprocal (shuffled from the lane that owns the row)
        #pragma unroll
        for (int r = 0; r < 4; ++r) {
            const float dv_ = __shfl(dinv, 16 * (si & 3) + 4 * r);
            float4 o = (r == 0) ? a0 : (r == 1) ? a1 : (r == 2) ? a2 : a3;
            o.x *= dv_; o.y *= dv_; o.z *= dv_; o.w *= dv_;
            *(float4*)(Outb + (size_t)(s0 + 4 * si + r) * D_ + 4 * vj) = o;
        }
    }
}

extern "C" void kernel_launch(void* const* d_in, const int* in_sizes, int n_in,
                              void* d_out, int out_size, void* d_ws, size_t ws_size,
                              hipStream_t stream) {
    const float* Q = (const float*)d_in[0];
    const float* K = (const float*)d_in[1];
    const float* V = (const float*)d_in[2];
    float* out = (float*)d_out;

    float* Mg = (float*)d_ws;                       // [BH][64][64]
    float* zg = Mg + (size_t)BH_ * 4096;            // [BH][64]
    const size_t init_bytes = ((size_t)BH_ * 4096 + (size_t)BH_ * 64) * sizeof(float);

    // ws is re-poisoned before every launch; zero the accumulators (capture-safe).
    hipMemsetAsync(d_ws, 0, init_bytes, stream);

    dim3 blk(256);
    dim3 g1(P1_CHUNKS, BH_);
    p1_kernel<<<g1, blk, 0, stream>>>(K, V, Mg, zg);

    dim3 g2(P2_CHUNKS, BH_);
    p2_kernel<<<g2, blk, 0, stream>>>(Q, Mg, zg, out);
}